// Round 7
// baseline (181.400 us; speedup 1.0000x reference)
//
#include <hip/hip_runtime.h>
#include <cstdint>

#define IDF 256
#define CDF 256
#define NL  128
#define HXW 4096
#define NB  32
#define PTILE 32

typedef _Float16 f16x8 __attribute__((ext_vector_type(8)));
typedef __fp16 fp16x2 __attribute__((ext_vector_type(2)));
typedef float f32x4 __attribute__((ext_vector_type(4)));
typedef unsigned short u16;
typedef unsigned int u32;

union Frag { f16x8 v; u32 u[4]; uint2 u2[2]; uint4 u4; };

__device__ __forceinline__ u16 f2h(float f) { union { _Float16 h; u16 s; } c; c.h = (_Float16)f; return c.s; }
__device__ __forceinline__ u32 pkrtz(float a, float b) {
  union { fp16x2 v; u32 u; } c;
  c.v = __builtin_amdgcn_cvt_pkrtz(a, b);
  return c.u;
}

// ws layout (bytes): [0..3] mode flag; [256..767] packed mask bits (32 rows x 4 u32);
// [1024 ..] srcF f16 [b][i][l] (2 MB); [+2MB ..] srcT f16 [b][l][i] (2 MB).

// ---------------- proj (+ fused mask prep in block (0,0)) ----------------
__global__ __launch_bounds__(256) void proj_kernel(const float* __restrict__ W,
                                                   const float* __restrict__ ctx,
                                                   u16* __restrict__ srcF,
                                                   u16* __restrict__ srcT,
                                                   const u32* __restrict__ msk,
                                                   u32* __restrict__ ws0) {
  const int tid = threadIdx.x;
  if (blockIdx.x == 0 && blockIdx.y == 0) {
    __shared__ int bi_s, bf_s, mode_s;
    if (tid == 0) { bi_s = 0; bf_s = 0; }
    __syncthreads();
    int bi = 0, bfl = 0;
    for (int k = 0; k < 4; ++k) {
      u32 v = msk[tid * 4 + k];
      if (v > 1u) bi = 1;
      float f = __uint_as_float(v);
      if (!(f == 0.0f || f == 1.0f)) bfl = 1;
    }
    if (bi) atomicOr(&bi_s, 1);
    if (bfl) atomicOr(&bf_s, 1);
    __syncthreads();
    if (tid == 0) { mode_s = (bi_s == 0) ? 0 : ((bf_s == 0) ? 1 : 2); ws0[0] = (u32)mode_s; }
    __syncthreads();
    const int mode = mode_s;
    if (tid < 128) {
      int row = tid >> 2, q = tid & 3;
      u32 bits = 0;
      for (int c = 0; c < 32; ++c) {
        int idx = row * NL + q * 32 + c;
        int mv;
        if (mode == 0)      mv = ((const int*)msk)[idx] != 0;
        else if (mode == 1) mv = ((const float*)msk)[idx] != 0.0f;
        else                mv = ((const unsigned char*)msk)[idx] != 0;
        bits |= (u32)mv << c;
      }
      ws0[64 + row * 4 + q] = bits;
    }
  }

  __shared__ float sWt[16][33];
  __shared__ float sC[16 * NL];
  const int b = blockIdx.y;
  const int i0 = blockIdx.x * 32;
  const int tx = tid & 31;
  const int ty = tid >> 5;
  float acc[4][4] = {};
  const float* ctxb = ctx + (size_t)b * CDF * NL;
  for (int c0 = 0; c0 < CDF; c0 += 16) {
    if (tid < 128) {
      int i = tid >> 2, cq = tid & 3;
      float4 w4 = *(const float4*)(W + (size_t)(i0 + i) * CDF + c0 + cq * 4);
      sWt[cq * 4 + 0][i] = w4.x; sWt[cq * 4 + 1][i] = w4.y;
      sWt[cq * 4 + 2][i] = w4.z; sWt[cq * 4 + 3][i] = w4.w;
    }
#pragma unroll
    for (int k = 0; k < 2; ++k) {
      int idx = tid + k * 256;
      int r = idx >> 5, c4 = idx & 31;
      *(float4*)(sC + r * NL + c4 * 4) =
          *(const float4*)(ctxb + (size_t)(c0 + r) * NL + c4 * 4);
    }
    __syncthreads();
#pragma unroll
    for (int cc = 0; cc < 16; ++cc) {
      float4 c4 = *(const float4*)(sC + cc * NL + tx * 4);
#pragma unroll
      for (int ii = 0; ii < 4; ++ii) {
        float w = sWt[cc][ty * 4 + ii];
        acc[ii][0] = fmaf(w, c4.x, acc[ii][0]);
        acc[ii][1] = fmaf(w, c4.y, acc[ii][1]);
        acc[ii][2] = fmaf(w, c4.z, acc[ii][2]);
        acc[ii][3] = fmaf(w, c4.w, acc[ii][3]);
      }
    }
    __syncthreads();
  }
  u16* sf = srcF + (size_t)b * IDF * NL;
  u16* st = srcT + (size_t)b * NL * IDF;
#pragma unroll
  for (int ii = 0; ii < 4; ++ii) {
    int i = i0 + ty * 4 + ii;
    u32 d0 = pkrtz(acc[ii][0], acc[ii][1]);
    u32 d1 = pkrtz(acc[ii][2], acc[ii][3]);
    *(uint2*)(sf + (size_t)i * NL + tx * 4) = make_uint2(d0, d1);
#pragma unroll
    for (int jl = 0; jl < 4; ++jl)
      st[(size_t)(tx * 4 + jl) * IDF + i] = f2h(acc[ii][jl]);
  }
}

// ---------------- fused attention, PTILE=32, wave-pair l-split ----------------
// waves: half = w>>1 (l half), wq = w&1 (p group). Lane owns column pl=wq*16+m15,
// rows l in [half*64, half*64+64). accq[4] (16 regs), accp[4][2] (32 regs).
// Phase1 srcT double-buffered; stores always issued AFTER the loads needed next.
__global__ __launch_bounds__(256, 4) void attn_kernel(
    const float* __restrict__ x, const u16* __restrict__ srcF,
    const u16* __restrict__ srcT, const u32* __restrict__ wsm,
    float* __restrict__ out0, float* __restrict__ out1) {
  __shared__ __align__(16) u32 sBuf[128 * 35];   // sXT [128 kp][35]; later sA [32][66]
  __shared__ float2 sM[2][32];                   // per-half (max, sum) per column

  const int tid = threadIdx.x;
  const int lane = tid & 63;
  const int w = tid >> 6;
  const int m15 = lane & 15;
  const int g = lane >> 4;
  const int half = w >> 1;       // l half: 0 -> l 0..63, 1 -> l 64..127
  const int wq = w & 1;          // p group
  const int b = blockIdx.y;
  const int p0 = blockIdx.x * PTILE;
  const int pl = wq * 16 + m15;  // p column owned by this lane: 0..31

  const u16* stb = srcT + (size_t)b * NL * IDF;

  // ---- phase 0: issue x loads (8 independent float4), then srcT ic=0; pack; barrier ----
  const float* xb = x + (size_t)b * IDF * HXW + p0;
  const int kq = tid >> 3;         // 0..31
  const int p4 = (tid & 7) * 4;    // p quad
  float4 lo[4], hi[4];
#pragma unroll
  for (int it = 0; it < 4; ++it) {
    const float* rp = xb + (size_t)(it * 64 + kq * 2) * HXW + p4;
    lo[it] = *(const float4*)rp;
    hi[it] = *(const float4*)(rp + HXW);
  }

  Frag bufA[4], bufB[4];
#define LOAD_ST(dst, ic_)                                                              \
  {                                                                                    \
    _Pragma("unroll")                                                                  \
    for (int nt = 0; nt < 4; ++nt)                                                     \
      dst[nt].u4 = *(const uint4*)(stb + (size_t)((half * 4 + nt) * 16 + m15) * IDF +  \
                                   (ic_) * 32 + g * 8);                                \
  }
  LOAD_ST(bufA, 0)

#pragma unroll
  for (int it = 0; it < 4; ++it) {
    int base = (it * 32 + kq) * 35 + p4;
    sBuf[base + 0] = pkrtz(lo[it].x, hi[it].x);
    sBuf[base + 1] = pkrtz(lo[it].y, hi[it].y);
    sBuf[base + 2] = pkrtz(lo[it].z, hi[it].z);
    sBuf[base + 3] = pkrtz(lo[it].w, hi[it].w);
  }
  __syncthreads();

  // ---- phase 1: logitsT[l][p] over K=256 in 8 chunks, srcT double-buffered ----
  f32x4 accq[4];
#pragma unroll
  for (int nt = 0; nt < 4; ++nt) accq[nt] = f32x4{0.f, 0.f, 0.f, 0.f};

#pragma unroll
  for (int ic = 0; ic < 8; ++ic) {
    if (ic < 7) {
      if (ic & 1) { LOAD_ST(bufA, ic + 1) } else { LOAD_ST(bufB, ic + 1) }
    }
    Frag bx;
#pragma unroll
    for (int jj = 0; jj < 4; ++jj)
      bx.u[jj] = sBuf[(ic * 16 + g * 4 + jj) * 35 + pl];
#pragma unroll
    for (int nt = 0; nt < 4; ++nt) {
      const Frag& af = (ic & 1) ? bufB[nt] : bufA[nt];
      accq[nt] = __builtin_amdgcn_mfma_f32_16x16x32_f16(af.v, bx.v, accq[nt], 0, 0, 0);
    }
  }

  // ---- phase 2: masked softmax, cross-half merge via sM ----
  const int rm = pl & 31;                       // mask row = p % 32
  uint4 mr = *(const uint4*)(wsm + rm * 4);
  u32 mwv[4] = {mr.x, mr.y, mr.z, mr.w};
  float mx = -3.0e38f;
#pragma unroll
  for (int nt = 0; nt < 4; ++nt) {
    int lt = half * 4 + nt;                     // l tile index 0..7
    u32 bits = mwv[lt >> 1] >> ((lt & 1) * 16);
#pragma unroll
    for (int r = 0; r < 4; ++r) {
      if ((bits >> (g * 4 + r)) & 1u) accq[nt][r] = -3.0e38f;
      mx = fmaxf(mx, accq[nt][r]);
    }
  }
  mx = fmaxf(mx, __shfl_xor(mx, 16));
  mx = fmaxf(mx, __shfl_xor(mx, 32));
  float s = 0.f;
#pragma unroll
  for (int nt = 0; nt < 4; ++nt)
#pragma unroll
    for (int r = 0; r < 4; ++r) {
      float e = __expf(accq[nt][r] - mx);
      accq[nt][r] = e;
      s += e;
    }
  s += __shfl_xor(s, 16);
  s += __shfl_xor(s, 32);
  if (g == 0) sM[half][pl] = make_float2(mx, s);
  __syncthreads();                              // sM ready; also ends all sXT reads
  float2 o = sM[half ^ 1][pl];
  float m = fmaxf(mx, o.x);
  float f = __expf(mx - m);
  float s_tot = s * f + o.y * __expf(o.x - m);
  const float inv = f / s_tot;                  // final = e * inv

  // ---- phase 3: normalize in regs; sA (alias sBuf) writes; barrier ----
  u32* sAd = sBuf;                              // sA [32 p][66] u32 (f16 l-pairs)
#pragma unroll
  for (int nt = 0; nt < 4; ++nt) {
#pragma unroll
    for (int r = 0; r < 4; ++r) accq[nt][r] *= inv;
    sAd[pl * 66 + (half * 4 + nt) * 8 + g * 2 + 0] = pkrtz(accq[nt][0], accq[nt][1]);
    sAd[pl * 66 + (half * 4 + nt) * 8 + g * 2 + 1] = pkrtz(accq[nt][2], accq[nt][3]);
  }
  __syncthreads();

  // ---- phase 4: PV. Issue srcF loads FIRST, then out1 stores, then MFMA ----
  const u16* sfb = srcF + (size_t)b * IDF * NL;
  Frag afA[4], afB[4];
#define LOAD_SF(dst, ks_)                                                              \
  {                                                                                    \
    _Pragma("unroll")                                                                  \
    for (int mt = 0; mt < 4; ++mt)                                                     \
      dst[mt].u4 = *(const uint4*)(sfb + (size_t)(w * 64 + mt * 16 + m15) * NL +       \
                                   (ks_) * 32 + g * 8);                                \
  }
  LOAD_SF(afA, 0)

  // out1 stores (issued after the ks=0 loads -> loads retire first, stores drain behind)
  float* o1 = out1 + (size_t)b * NL * HXW + p0 + pl;
#pragma unroll
  for (int nt = 0; nt < 4; ++nt)
#pragma unroll
    for (int r = 0; r < 4; ++r)
      o1[(size_t)((half * 4 + nt) * 16 + g * 4 + r) * HXW] = accq[nt][r];

  f32x4 accp[4][2];
#pragma unroll
  for (int mt = 0; mt < 4; ++mt)
#pragma unroll
    for (int n2 = 0; n2 < 2; ++n2) accp[mt][n2] = f32x4{0.f, 0.f, 0.f, 0.f};

#pragma unroll
  for (int ks = 0; ks < 4; ++ks) {
    if (ks < 3) {
      if (ks & 1) { LOAD_SF(afA, ks + 1) } else { LOAD_SF(afB, ks + 1) }
    }
    Frag bf[2];
#pragma unroll
    for (int n2 = 0; n2 < 2; ++n2) {
      int di = (n2 * 16 + m15) * 66 + ks * 16 + g * 4;
      bf[n2].u2[0] = *(const uint2*)(sAd + di);
      bf[n2].u2[1] = *(const uint2*)(sAd + di + 2);
    }
#pragma unroll
    for (int mt = 0; mt < 4; ++mt) {
      const Frag& af = (ks & 1) ? afB[mt] : afA[mt];
#pragma unroll
      for (int n2 = 0; n2 < 2; ++n2)
        accp[mt][n2] = __builtin_amdgcn_mfma_f32_16x16x32_f16(af.v, bf[n2].v, accp[mt][n2], 0, 0, 0);
    }
  }

  float* o0 = out0 + (size_t)b * IDF * HXW + p0;
#pragma unroll
  for (int mt = 0; mt < 4; ++mt)
#pragma unroll
    for (int n2 = 0; n2 < 2; ++n2) {
      int col = n2 * 16 + m15;
#pragma unroll
      for (int r = 0; r < 4; ++r) {
        int row = w * 64 + mt * 16 + g * 4 + r;
        o0[(size_t)row * HXW + col] = accp[mt][n2][r];
      }
    }
}

extern "C" void kernel_launch(void* const* d_in, const int* in_sizes, int n_in,
                              void* d_out, int out_size, void* d_ws, size_t ws_size,
                              hipStream_t stream) {
  const float* x   = (const float*)d_in[0];
  const float* ctx = (const float*)d_in[1];
  const float* W   = (const float*)d_in[2];
  const void*  msk = d_in[3];
  float* out0 = (float*)d_out;                       // [32][256][64][64]
  float* out1 = out0 + (size_t)NB * IDF * HXW;       // [32][128][64][64]
  u32* ws0 = (u32*)d_ws;
  u16* srcF = (u16*)((char*)d_ws + 1024);            // [32][256][128] f16
  u16* srcT = (u16*)((char*)d_ws + 1024 + 2097152);  // [32][128][256] f16

  proj_kernel<<<dim3(8, NB), 256, 0, stream>>>(W, ctx, srcF, srcT, (const u32*)msk, ws0);
  attn_kernel<<<dim3(HXW / PTILE, NB), 256, 0, stream>>>(x, srcF, srcT, ws0 + 64, out0, out1);
}